// Round 21
// baseline (213.554 us; speedup 1.0000x reference)
//
#include <hip/hip_runtime.h>

// B=32768, K=16, D=256, H=2, HD=128
#define Bsz 32768
#define BR  32           // rows per block
#define SCALE 0.08838834764831845f   // 1/sqrt(128)

typedef __attribute__((ext_vector_type(4))) float f32x4;
typedef __attribute__((ext_vector_type(4))) unsigned short us4;
typedef __attribute__((ext_vector_type(8))) unsigned short us8;
typedef __attribute__((ext_vector_type(4))) unsigned int ui4;
typedef __attribute__((ext_vector_type(2))) unsigned int ui2;
typedef _Float16 __attribute__((ext_vector_type(2))) h2;
typedef _Float16 __attribute__((ext_vector_type(8))) h8;

static __device__ __forceinline__ unsigned int pk16(float a, float b){
  return __builtin_bit_cast(unsigned int, __builtin_amdgcn_cvt_pkrtz(a, b));
}
static __device__ __forceinline__ h2 uph(unsigned int u){
  return __builtin_bit_cast(h2, u);
}
static __device__ __forceinline__ float h2f(unsigned short h){
  return (float)__builtin_bit_cast(_Float16, h);
}
static __device__ __forceinline__ unsigned short f16b(float x){
  return __builtin_bit_cast(unsigned short, (_Float16)x);
}
static __device__ __forceinline__ h8 ldh8(const unsigned short* p){
  return __builtin_bit_cast(h8, *(const us8*)p);
}
#define MFMA16(a, b, c) __builtin_amdgcn_mfma_f32_16x16x32_f16((a), (b), (c), 0, 0, 0)

// ---------------------------------------------------------------------------
// Prep: ALL weights ROW-MAJOR f16 (MFMA B-fragments).
//   W1R us [640][256]: rows 0..511 -> M_h rows (n=h*256+m); 512..639 -> Wc
//   W2R us [256][256]: Wv row-major
//   W3R us [128][256]: Wx row-major
// ws total: (640+256+128)*256*2 = 512 KiB.
// ---------------------------------------------------------------------------
__global__ void prep_kernel(const float* __restrict__ Wq, const float* __restrict__ Wk,
                            const float* __restrict__ Wv, const float* __restrict__ Wc,
                            const float* __restrict__ Wx, unsigned short* __restrict__ wsp){
  unsigned short* W1R = wsp;                                   // [640][256]
  unsigned short* W2R = wsp + 640*256;                         // [256][256]
  unsigned short* W3R = W2R + 256*256;                         // [128][256]
  const int n = blockIdx.x;
  const int k = threadIdx.x;
  float val;
  if (n < 512){
    const int h = n >> 8, m = n & 255;
    const float* wq = Wq + h*128*256 + k;
    const float* wk = Wk + h*128*256 + m;
    float s = 0.f;
    for (int d = 0; d < 128; ++d) s += wq[d*256] * wk[d*256];
    val = s;
  } else if (n < 640){
    val = Wc[(n-512)*256 + k];
  } else if (n < 896){
    val = Wv[(n-640)*256 + k];
  } else {
    val = Wx[(n-896)*256 + k];
  }
  if (n < 640)      W1R[n*256 + k] = f16b(val);
  else if (n < 896) W2R[(n-640)*256 + k] = f16b(val);
  else              W3R[(n-896)*256 + k] = f16b(val);
}

// ---------------------------------------------------------------------------
// Fused kernel. Phases A/C/E all via MFMA (each validated incrementally,
// R18/R19/R20); phase B attention verbatim R12. In-register LayerNorm after C
// (shfl partials + 16B/row LDS exchange, R20-proven).
// Wave roles in A/C/E: rowg=wid>>1 (16-row group), colh=wid&1 (column half).
// LDS s_ctil us[32][520]: center f16 (cells 256..511) -> ctil 0..511 (A..B)
//   -> wbuf+agg (B..C) -> LN partials cells 256..263 -> ctx_n f16 cells 0..255.
// ---------------------------------------------------------------------------
__global__ __launch_bounds__(256, 4) void fused_kernel(
    const float* __restrict__ center, const float* __restrict__ nbr,
    const float* __restrict__ ew, const float* __restrict__ gamma,
    const float* __restrict__ beta, const unsigned short* __restrict__ Wall,
    float* __restrict__ out)
{
  __shared__ __align__(16) unsigned short s_ctil[BR*520];

  const int tid  = threadIdx.x;
  const int wid  = tid >> 6;
  const int lane = tid & 63;
  const int b0   = blockIdx.x * BR;

  const unsigned short* W1R = Wall;               // [640][256]
  const unsigned short* W2R = Wall + 640*256;     // [256][256]
  const unsigned short* W3R = W2R + 256*256;      // [128][256]

  // ---- stage center rows 8w..8w+7 as f16 -> cells 256..511 ----
  {
    const int sr = tid >> 3;            // 0..31, wave-local rows
    const int fc = (tid & 7) * 32;      // f16 col base
    const float* cp = center + ((long)(b0 + sr) << 8) + fc;
    #pragma unroll
    for (int it = 0; it < 4; ++it){
      float4 a = *(const float4*)(cp + it*8);
      float4 b = *(const float4*)(cp + it*8 + 4);
      ui4 v = {pk16(a.x,a.y), pk16(a.z,a.w), pk16(b.x,b.y), pk16(b.z,b.w)};
      *(ui4*)&s_ctil[sr*520 + 256 + fc + it*8] = v;
    }
  }
  __syncthreads();

  // ---- Phase A via MFMA: [32x256]@[256x640] -> ctil (LDS) + out-left ----
  {
    const int rowg = wid >> 1;       // 16-row group
    const int colh = wid & 1;        // 20-tile column half
    const int l15 = lane & 15, lq = lane >> 4;
    h8 af[8];
    #pragma unroll
    for (int kk = 0; kk < 8; ++kk)
      af[kk] = __builtin_bit_cast(h8,
        *(const us8*)&s_ctil[(rowg*16 + l15)*520 + 256 + kk*32 + lq*8]);
    __syncthreads();   // all fragment loads done before ctil overwrites cells 256+
    #pragma unroll 1
    for (int c0t = 0; c0t < 20; c0t += 5){
      f32x4 acc[5];
      #pragma unroll
      for (int u = 0; u < 5; ++u) acc[u] = (f32x4){0,0,0,0};
      #pragma unroll
      for (int kk = 0; kk < 8; ++kk)
        #pragma unroll
        for (int u = 0; u < 5; ++u){
          const int gt = colh*20 + c0t + u;
          acc[u] = MFMA16(af[kk], ldh8(W1R + (gt*16 + l15)*256 + kk*32 + lq*8), acc[u]);
        }
      #pragma unroll
      for (int u = 0; u < 5; ++u){
        const int gt = colh*20 + c0t + u;
        if (gt < 32){
          #pragma unroll
          for (int j = 0; j < 4; ++j)
            s_ctil[(rowg*16 + lq*4 + j)*520 + gt*16 + l15] = f16b(acc[u][j]);
        } else {
          #pragma unroll
          for (int j = 0; j < 4; ++j)
            out[((long)(b0 + rowg*16 + lq*4 + j) << 8) + (gt-32)*16 + l15] = acc[u][j];
        }
      }
    }
  }
  __syncthreads();

  // ---- Phase B: attention (VERBATIM round 12), 8 rows/wave ----
  {
    const int myk = ((lane>>4)&1)*8 + ((lane>>3)&1)*4 + ((lane>>2)&1)*2 + ((lane>>1)&1);
    const int myh = lane >> 5;
    #pragma unroll 1
    for (int rr = 0; rr < 8; ++rr){
      const int r = wid*8 + rr;
      const long b = b0 + r;
      float4 c0, c1;
      {
        us4 h0 = *(const us4*)&s_ctil[r*520 + lane*4];
        us4 h1 = *(const us4*)&s_ctil[r*520 + 256 + lane*4];
        c0.x=h2f(h0[0]); c0.y=h2f(h0[1]); c0.z=h2f(h0[2]); c0.w=h2f(h0[3]);
        c1.x=h2f(h1[0]); c1.y=h2f(h1[1]); c1.z=h2f(h1[2]); c1.w=h2f(h1[3]);
      }
      float4 xv[16];
      const float* npt = nbr + ((b << 4) << 8) + lane*4;
      #pragma unroll
      for (int k = 0; k < 16; ++k) xv[k] = *(const float4*)(npt + (k << 8));
      float P0[16], P1[16];
      #pragma unroll
      for (int k = 0; k < 16; ++k){
        P0[k] = xv[k].x*c0.x + xv[k].y*c0.y + xv[k].z*c0.z + xv[k].w*c0.w;
        P1[k] = xv[k].x*c1.x + xv[k].y*c1.y + xv[k].z*c1.z + xv[k].w*c1.w;
      }
      // reduce-scatter: masks 32,16,8,4,2, then final 1
      const int b5 = lane & 32, b4 = lane & 16, b3 = lane & 8, b2 = lane & 4, b1 = lane & 2;
      float Q[16];
      #pragma unroll
      for (int j = 0; j < 16; ++j){
        const float give = b5 ? P0[j] : P1[j];
        const float keep = b5 ? P1[j] : P0[j];
        Q[j] = keep + __shfl_xor(give, 32, 64);
      }
      float R[8];
      #pragma unroll
      for (int j = 0; j < 8; ++j){
        const float give = b4 ? Q[j] : Q[8+j];
        const float keep = b4 ? Q[8+j] : Q[j];
        R[j] = keep + __shfl_xor(give, 16, 64);
      }
      float S[4];
      #pragma unroll
      for (int j = 0; j < 4; ++j){
        const float give = b3 ? R[j] : R[4+j];
        const float keep = b3 ? R[4+j] : R[j];
        S[j] = keep + __shfl_xor(give, 8, 64);
      }
      float T[2];
      #pragma unroll
      for (int j = 0; j < 2; ++j){
        const float give = b2 ? S[j] : S[2+j];
        const float keep = b2 ? S[2+j] : S[j];
        T[j] = keep + __shfl_xor(give, 4, 64);
      }
      float U;
      {
        const float give = b1 ? T[0] : T[1];
        const float keep = b1 ? T[1] : T[0];
        U = keep + __shfl_xor(give, 2, 64);
      }
      const float sfull = U + __shfl_xor(U, 1, 64);   // s[myh][myk]
      const float erk = ew[b*16 + myk];
      const float e = __expf(sfull*SCALE + erk);      // scores O(1): no max-sub
      float dn = e;
      dn += __shfl_xor(dn, 2, 64);
      dn += __shfl_xor(dn, 4, 64);
      dn += __shfl_xor(dn, 8, 64);
      dn += __shfl_xor(dn, 16, 64);
      const float w = e / dn;
      // broadcast via wave-local overlay of head1-ctil cells (c1 already read)
      float* wbuf = (float*)&s_ctil[r*520 + 256];
      wbuf[myh*16 + myk] = w;                         // 2 lanes same addr, same value
      f32x4 wv[8];
      #pragma unroll
      for (int t = 0; t < 8; ++t) wv[t] = ((const f32x4*)wbuf)[t];
      float4 agg0 = {0,0,0,0}, agg1 = {0,0,0,0};
      #pragma unroll
      for (int k = 0; k < 16; ++k){
        const float w0 = wv[k>>2][k&3];
        const float w1 = wv[4 + (k>>2)][k&3];
        agg0.x += w0*xv[k].x; agg0.y += w0*xv[k].y; agg0.z += w0*xv[k].z; agg0.w += w0*xv[k].w;
        agg1.x += w1*xv[k].x; agg1.y += w1*xv[k].y; agg1.z += w1*xv[k].z; agg1.w += w1*xv[k].w;
      }
      ui2 v0 = {pk16(agg0.x, agg0.y), pk16(agg0.z, agg0.w)};
      ui2 v1 = {pk16(agg1.x, agg1.y), pk16(agg1.z, agg1.w)};
      *(ui2*)&s_ctil[r*520 + lane*4]       = v0;   // agg0 (WAR on own cells)
      *(ui2*)&s_ctil[r*520 + 256 + lane*4] = v1;   // agg1 (overwrites wbuf after read)
    }
  }
  __syncthreads();   // agg complete; phase C reads cross-wave rows

  // ---- Phase C via MFMA + in-register LayerNorm -> ctx_n f16 (cells 0..255) ----
  {
    const int rowg = wid >> 1;       // 16-row group
    const int colh = wid & 1;        // column half (== head)
    const int l15 = lane & 15, lq = lane >> 4;
    h8 cf[8];
    #pragma unroll
    for (int kk = 0; kk < 8; ++kk)
      cf[kk] = __builtin_bit_cast(h8,
        *(const us8*)&s_ctil[(rowg*16 + l15)*520 + colh*256 + kk*32 + lq*8]);
    f32x4 cacc[8];
    #pragma unroll
    for (int t = 0; t < 8; ++t) cacc[t] = (f32x4){0,0,0,0};
    #pragma unroll
    for (int kk = 0; kk < 8; ++kk)
      #pragma unroll
      for (int t = 0; t < 8; ++t){
        const int col = colh*128 + t*16 + l15;      // ctx col (head = colh)
        cacc[t] = MFMA16(cf[kk], ldh8(W2R + col*256 + kk*32 + lq*8), cacc[t]);
      }
    // partial row sums over this wave's 128-col half (reduce across l15)
    float ps[4], pq[4];
    #pragma unroll
    for (int j = 0; j < 4; ++j){
      float sm = 0.f, qm = 0.f;
      #pragma unroll
      for (int t = 0; t < 8; ++t){ const float x = cacc[t][j]; sm += x; qm += x*x; }
      #pragma unroll
      for (int m = 1; m <= 8; m <<= 1){
        sm += __shfl_xor(sm, m, 64);
        qm += __shfl_xor(qm, m, 64);
      }
      ps[j] = sm; pq[j] = qm;
    }
    __syncthreads();   // all cf reads done before partial writes hit cells 256..263
    if (l15 == 0){
      #pragma unroll
      for (int j = 0; j < 4; ++j){
        float* pp = (float*)&s_ctil[(rowg*16 + lq*4 + j)*520 + 256];
        pp[colh*2]     = ps[j];
        pp[colh*2 + 1] = pq[j];
      }
    }
    __syncthreads();   // partials visible to the wave pair
    float gv[8], bv[8];
    #pragma unroll
    for (int t = 0; t < 8; ++t){
      const int col = colh*128 + t*16 + l15;
      gv[t] = gamma[col];
      bv[t] = beta[col];
    }
    #pragma unroll
    for (int j = 0; j < 4; ++j){
      const int r = rowg*16 + lq*4 + j;
      const float* pp = (const float*)&s_ctil[r*520 + 256];
      const float sm = pp[0] + pp[2];
      const float qm = pp[1] + pp[3];
      const float mu  = sm * (1.f/256.f);
      const float var = qm * (1.f/256.f) - mu*mu;
      const float rs  = rsqrtf(var + 1e-5f);
      #pragma unroll
      for (int t = 0; t < 8; ++t){
        const int col = colh*128 + t*16 + l15;
        s_ctil[r*520 + col] = f16b((cacc[t][j] - mu)*rs*gv[t] + bv[t]);
      }
    }
  }
  __syncthreads();   // ctx_n complete (both halves) before E

  // ---- Phase E via MFMA: out-right = ctx_n @ Wx^T ----
  {
    const int rowg = wid >> 1;       // 16-row group
    const int colh = wid & 1;        // 64-col half
    const int l15 = lane & 15, lq = lane >> 4;
    h8 ef[8];
    #pragma unroll
    for (int kk = 0; kk < 8; ++kk)
      ef[kk] = __builtin_bit_cast(h8,
        *(const us8*)&s_ctil[(rowg*16 + l15)*520 + kk*32 + lq*8]);
    f32x4 eacc[4];
    #pragma unroll
    for (int t = 0; t < 4; ++t) eacc[t] = (f32x4){0,0,0,0};
    #pragma unroll
    for (int kk = 0; kk < 8; ++kk)
      #pragma unroll
      for (int t = 0; t < 4; ++t){
        const int col = colh*64 + t*16 + l15;       // 0..127
        eacc[t] = MFMA16(ef[kk], ldh8(W3R + col*256 + kk*32 + lq*8), eacc[t]);
      }
    #pragma unroll
    for (int t = 0; t < 4; ++t)
      #pragma unroll
      for (int j = 0; j < 4; ++j)
        out[((long)(b0 + rowg*16 + lq*4 + j) << 8) + 128 + colh*64 + t*16 + l15] = eacc[t][j];
  }
}

extern "C" void kernel_launch(void* const* d_in, const int* in_sizes, int n_in,
                              void* d_out, int out_size, void* d_ws, size_t ws_size,
                              hipStream_t stream){
  const float* center = (const float*)d_in[0];
  const float* nbr    = (const float*)d_in[1];
  const float* ew     = (const float*)d_in[2];
  const float* Wq     = (const float*)d_in[3];
  const float* Wk     = (const float*)d_in[4];
  const float* Wv     = (const float*)d_in[5];
  const float* Wc     = (const float*)d_in[6];
  const float* Wx     = (const float*)d_in[7];
  const float* gamma  = (const float*)d_in[8];
  const float* beta   = (const float*)d_in[9];
  (void)in_sizes; (void)n_in; (void)out_size;

  unsigned short* W = (unsigned short*)d_ws;   // 512 KiB of workspace
  (void)ws_size;

  prep_kernel<<<1024, 256, 0, stream>>>(Wq, Wk, Wv, Wc, Wx, W);
  fused_kernel<<<Bsz/BR, 256, 0, stream>>>(center, nbr, ew, gamma, beta, W, (float*)d_out);
}